// Round 1
// baseline (1794.984 us; speedup 1.0000x reference)
//
#include <hip/hip_runtime.h>

// Problem constants
#define B_SZ  8192
#define E_DIM 256
#define N_E   4096
#define N_L   3

// Output layout (float offsets), concatenated in reference return order:
// x_q [8192,256], loss [1], idx [8192,3], one_hot [8192,3,4096], logits [8192,3,4096]
#define XQ_OFF   0
#define LOSS_OFF 2097152
#define IDX_OFF  2097153
#define OH_OFF   2121729
#define LG_OFF   102785025

// Workspace layout (bytes): keys[8192]u64 @0, rn[8192]f32 @65536,
// cn[3*4096]f32 @98304, loss f32 @147456. Total 147460 B.

// ---------------------------------------------------------------- init: residual = x, rn = ||x||^2
__global__ __launch_bounds__(256) void init_resid(const float* __restrict__ x,
                                                  float* __restrict__ resid,
                                                  float* __restrict__ rn) {
    const int b = blockIdx.x, t = threadIdx.x;
    const float v = x[(size_t)b * E_DIM + t];
    resid[(size_t)b * E_DIM + t] = v;
    float s = v * v;
#pragma unroll
    for (int o = 32; o; o >>= 1) s += __shfl_down(s, o);
    __shared__ float red[4];
    if ((t & 63) == 0) red[t >> 6] = s;
    __syncthreads();
    if (t == 0) rn[b] = red[0] + red[1] + red[2] + red[3];
}

// ---------------------------------------------------------------- codebook row norms (all 3 layers)
__global__ __launch_bounds__(64) void cb_norms(const float* __restrict__ cb,
                                               float* __restrict__ cn) {
    const int row = blockIdx.x;   // 0..12287
    const int t = threadIdx.x;    // 64 threads, float4 each -> 256 elems
    const float4 v = ((const float4*)(cb + (size_t)row * E_DIM))[t];
    float s = v.x * v.x + v.y * v.y + v.z * v.z + v.w * v.w;
#pragma unroll
    for (int o = 32; o; o >>= 1) s += __shfl_down(s, o);
    if (t == 0) cn[row] = s;
}

// ---------------------------------------------------------------- distance GEMM + logits + argmin
// d[b][j] = rn[b] + cn[j] - 2 * dot(R[b], C[j]); tile 64x64, BK=16, 256 threads, 4x4 micro-tile.
#define BM 64
#define BN 64
#define BK 16
#define LDP 68   // padded LDS leading dim (keeps 16B alignment, 2-way conflicts only = free)

__global__ __launch_bounds__(256) void dist_gemm(
    const float* __restrict__ R, const float* __restrict__ C,
    const float* __restrict__ rn, const float* __restrict__ cn,
    float* __restrict__ logits, unsigned long long* __restrict__ keys, int layer) {
    __shared__ float As[BK][LDP];
    __shared__ float Bs[BK][LDP];
    const int tid = threadIdx.x;
    const int tx = tid & 15, ty = tid >> 4;
    const int bm = blockIdx.y * BM, bn = blockIdx.x * BN;
    const int lr = tid >> 2;          // load row 0..63
    const int lc = (tid & 3) * 4;     // load k-chunk {0,4,8,12}

    const float* Ap = R + (size_t)(bm + lr) * E_DIM + lc;
    const float* Bp = C + (size_t)(bn + lr) * E_DIM + lc;

    float acc[4][4] = {};

    for (int k0 = 0; k0 < E_DIM; k0 += BK) {
        const float4 a = *(const float4*)(Ap + k0);
        const float4 b = *(const float4*)(Bp + k0);
        __syncthreads();
        As[lc + 0][lr] = a.x; As[lc + 1][lr] = a.y; As[lc + 2][lr] = a.z; As[lc + 3][lr] = a.w;
        Bs[lc + 0][lr] = b.x; Bs[lc + 1][lr] = b.y; Bs[lc + 2][lr] = b.z; Bs[lc + 3][lr] = b.w;
        __syncthreads();
#pragma unroll
        for (int k = 0; k < BK; ++k) {
            const float4 av = *(const float4*)&As[k][ty * 4];
            const float4 bv = *(const float4*)&Bs[k][tx * 4];
            acc[0][0] += av.x * bv.x; acc[0][1] += av.x * bv.y; acc[0][2] += av.x * bv.z; acc[0][3] += av.x * bv.w;
            acc[1][0] += av.y * bv.x; acc[1][1] += av.y * bv.y; acc[1][2] += av.y * bv.z; acc[1][3] += av.y * bv.w;
            acc[2][0] += av.z * bv.x; acc[2][1] += av.z * bv.y; acc[2][2] += av.z * bv.z; acc[2][3] += av.z * bv.w;
            acc[3][0] += av.w * bv.x; acc[3][1] += av.w * bv.y; acc[3][2] += av.w * bv.z; acc[3][3] += av.w * bv.w;
        }
    }

    float rnv[4], cnv[4];
#pragma unroll
    for (int i = 0; i < 4; ++i) rnv[i] = rn[bm + ty * 4 + i];
#pragma unroll
    for (int j = 0; j < 4; ++j) cnv[j] = cn[bn + tx * 4 + j];

#pragma unroll
    for (int i = 0; i < 4; ++i) {
        const int row = bm + ty * 4 + i;
        float* lrow = logits + ((size_t)(row * N_L + layer)) * N_E + bn;
        float dmin = 1e30f;
        int jmin = 0;
#pragma unroll
        for (int j = 0; j < 4; ++j) {
            const float d = rnv[i] + cnv[j] - 2.0f * acc[i][j];
            lrow[tx * 4 + j] = d;
            if (d < dmin) { dmin = d; jmin = bn + tx * 4 + j; }   // ascending j: first-min
        }
        // min-reduce (distance, lowest index on tie) across the 16 lanes covering this row
        unsigned long long key =
            ((unsigned long long)__float_as_uint(dmin) << 32) | (unsigned)jmin;
#pragma unroll
        for (int o = 8; o; o >>= 1) {
            const unsigned long long other = __shfl_xor(key, o);
            if (other < key) key = other;
        }
        if (tx == 0) atomicMin(&keys[row], key);
    }
}

// ---------------------------------------------------------------- per-row update after argmin
__global__ __launch_bounds__(256) void vq_update(
    const float* __restrict__ C, const unsigned long long* __restrict__ keys,
    float* __restrict__ resid, float* __restrict__ rn,
    float* __restrict__ out_idx, float* __restrict__ oh,
    float* __restrict__ loss_ws, int layer) {
    const int b = blockIdx.x, t = threadIdx.x;
    const unsigned long long key = keys[b];
    const int j = (int)(key & 0xFFFFFFFFull);
    const float q = C[(size_t)j * E_DIM + t];
    const float r = resid[(size_t)b * E_DIM + t];
    const float nr = r - q;                      // new residual; (q-r)^2 == nr^2 -> loss term
    resid[(size_t)b * E_DIM + t] = nr;
    float s = nr * nr;
#pragma unroll
    for (int o = 32; o; o >>= 1) s += __shfl_down(s, o);
    __shared__ float red[4];
    if ((t & 63) == 0) red[t >> 6] = s;
    __syncthreads();
    if (t == 0) {
        const float tot = red[0] + red[1] + red[2] + red[3];
        rn[b] = tot;                             // ||new residual||^2 = next layer's rn
        atomicAdd(loss_ws, tot);
        out_idx[b * N_L + layer] = (float)j;
        oh[((size_t)(b * N_L + layer)) * N_E + j] = 1.0f;
    }
}

// ---------------------------------------------------------------- x_q = x - residual (in place), loss
__global__ __launch_bounds__(256) void finalize(const float* __restrict__ x,
                                                float* __restrict__ xq,
                                                const float* __restrict__ loss_ws,
                                                float* __restrict__ loss_out) {
    const int i = blockIdx.x * 256 + threadIdx.x;   // float4 index, 2048 blocks
    const float4 xv = ((const float4*)x)[i];
    const float4 rv = ((const float4*)xq)[i];
    float4 o;
    o.x = xv.x - rv.x; o.y = xv.y - rv.y; o.z = xv.z - rv.z; o.w = xv.w - rv.w;
    ((float4*)xq)[i] = o;
    if (i == 0)
        loss_out[0] = 1.25f * loss_ws[0] / (3.0f * B_SZ * E_DIM);
}

extern "C" void kernel_launch(void* const* d_in, const int* in_sizes, int n_in,
                              void* d_out, int out_size, void* d_ws, size_t ws_size,
                              hipStream_t stream) {
    (void)in_sizes; (void)n_in; (void)out_size; (void)ws_size;
    const float* x  = (const float*)d_in[0];
    const float* cb = (const float*)d_in[1];
    float* out = (float*)d_out;

    float* resid    = out + XQ_OFF;     // residual lives in the x_q output region
    float* loss_out = out + LOSS_OFF;
    float* idx_out  = out + IDX_OFF;
    float* oh       = out + OH_OFF;
    float* lg       = out + LG_OFF;

    unsigned long long* keys = (unsigned long long*)d_ws;
    float* rn      = (float*)((char*)d_ws + 65536);
    float* cn      = (float*)((char*)d_ws + 98304);
    float* loss_ws = (float*)((char*)d_ws + 147456);

    // one_hot region is poisoned 0xAA every call -> zero it (24576 ones scattered later)
    hipMemsetAsync(oh, 0, (size_t)B_SZ * N_L * N_E * sizeof(float), stream);
    hipMemsetAsync(loss_ws, 0, sizeof(float), stream);

    init_resid<<<B_SZ, 256, 0, stream>>>(x, resid, rn);
    cb_norms<<<N_L * N_E, 64, 0, stream>>>(cb, cn);

    for (int l = 0; l < N_L; ++l) {
        hipMemsetAsync(keys, 0xFF, B_SZ * sizeof(unsigned long long), stream);
        dim3 grid(N_E / BN, B_SZ / BM);
        dist_gemm<<<grid, 256, 0, stream>>>(resid, cb + (size_t)l * N_E * E_DIM,
                                            rn, cn + l * N_E, lg, keys, l);
        vq_update<<<B_SZ, 256, 0, stream>>>(cb + (size_t)l * N_E * E_DIM, keys,
                                            resid, rn, idx_out, oh, loss_ws, l);
    }
    finalize<<<B_SZ * E_DIM / 4 / 256, 256, 0, stream>>>(x, resid, loss_ws, loss_out);
}

// Round 2
// 1683.333 us; speedup vs baseline: 1.0663x; 1.0663x over previous
//
#include <hip/hip_runtime.h>

// Problem constants
#define B_SZ  8192
#define E_DIM 256
#define N_E   4096
#define N_L   3

// Output layout (float offsets), concatenated in reference return order:
// x_q [8192,256], loss [1], idx [8192,3], one_hot [8192,3,4096], logits [8192,3,4096]
#define XQ_OFF   0
#define LOSS_OFF 2097152
#define IDX_OFF  2097153
#define OH_OFF   2121729
#define LG_OFF   102785025

// Workspace layout (bytes): keys[8192]u64 @0, rn[8192]f32 @65536,
// cn[3*4096]f32 @98304, loss f32 @147456.

// ---------------------------------------------------------------- init: residual = x, rn = ||x||^2
__global__ __launch_bounds__(256) void init_resid(const float* __restrict__ x,
                                                  float* __restrict__ resid,
                                                  float* __restrict__ rn) {
    const int b = blockIdx.x, t = threadIdx.x;
    const float v = x[(size_t)b * E_DIM + t];
    resid[(size_t)b * E_DIM + t] = v;
    float s = v * v;
#pragma unroll
    for (int o = 32; o; o >>= 1) s += __shfl_down(s, o);
    __shared__ float red[4];
    if ((t & 63) == 0) red[t >> 6] = s;
    __syncthreads();
    if (t == 0) rn[b] = red[0] + red[1] + red[2] + red[3];
}

// ---------------------------------------------------------------- codebook row norms (all 3 layers)
__global__ __launch_bounds__(64) void cb_norms(const float* __restrict__ cb,
                                               float* __restrict__ cn) {
    const int row = blockIdx.x;   // 0..12287
    const int t = threadIdx.x;    // 64 threads, float4 each -> 256 elems
    const float4 v = ((const float4*)(cb + (size_t)row * E_DIM))[t];
    float s = v.x * v.x + v.y * v.y + v.z * v.z + v.w * v.w;
#pragma unroll
    for (int o = 32; o; o >>= 1) s += __shfl_down(s, o);
    if (t == 0) cn[row] = s;
}

// ---------------------------------------------------------------- distance GEMM + logits + one_hot-zero + argmin
// d[b][j] = rn[b] + cn[j] - 2*dot(R[b],C[j]); tile 128x128, BK=32, 256 threads, 8x8 micro-tile
// (split as 4+4 rows/cols for contiguous epilogue stores).
#define TM 128
#define TN 128
#define TK 32
#define LDP 132   // 132%32=4 -> transpose-store conflicts capped at 4-way; rows stay 16B-aligned

__global__ __launch_bounds__(256) void dist_gemm(
    const float* __restrict__ R, const float* __restrict__ C,
    const float* __restrict__ rn, const float* __restrict__ cn,
    float* __restrict__ logits, float* __restrict__ oh,
    unsigned long long* __restrict__ keys, int layer) {
    __shared__ float As[TK][LDP];
    __shared__ float Bs[TK][LDP];
    const int tid = threadIdx.x;
    const int kq = tid & 7;        // float4 chunk within BK (0..7)
    const int r0 = tid >> 3;       // tile row 0..31 (+32m)
    const int tx = tid & 15, ty = tid >> 4;
    const int bm = blockIdx.y * TM, bn = blockIdx.x * TN;

    const float* Ap = R + (size_t)(bm + r0) * E_DIM + kq * 4;
    const float* Bp = C + (size_t)(bn + r0) * E_DIM + kq * 4;

    float4 a[4], b[4];
#pragma unroll
    for (int m = 0; m < 4; ++m) {       // preload k0 = 0
        a[m] = *(const float4*)(Ap + (size_t)m * 32 * E_DIM);
        b[m] = *(const float4*)(Bp + (size_t)m * 32 * E_DIM);
    }

    float acc[8][8] = {};

    for (int k0 = 0; k0 < E_DIM; k0 += TK) {
        __syncthreads();                 // previous tile's readers done
#pragma unroll
        for (int m = 0; m < 4; ++m) {
#pragma unroll
            for (int i = 0; i < 4; ++i) {
                As[kq * 4 + i][r0 + 32 * m] = ((const float*)&a[m])[i];
                Bs[kq * 4 + i][r0 + 32 * m] = ((const float*)&b[m])[i];
            }
        }
        __syncthreads();
        if (k0 + TK < E_DIM) {           // prefetch next tile while computing this one
#pragma unroll
            for (int m = 0; m < 4; ++m) {
                a[m] = *(const float4*)(Ap + k0 + TK + (size_t)m * 32 * E_DIM);
                b[m] = *(const float4*)(Bp + k0 + TK + (size_t)m * 32 * E_DIM);
            }
        }
#pragma unroll 8
        for (int k = 0; k < TK; ++k) {
            const float4 av0 = *(const float4*)&As[k][ty * 4];
            const float4 av1 = *(const float4*)&As[k][64 + ty * 4];
            const float4 bv0 = *(const float4*)&Bs[k][tx * 4];
            const float4 bv1 = *(const float4*)&Bs[k][64 + tx * 4];
            const float am[8] = {av0.x, av0.y, av0.z, av0.w, av1.x, av1.y, av1.z, av1.w};
            const float bj[8] = {bv0.x, bv0.y, bv0.z, bv0.w, bv1.x, bv1.y, bv1.z, bv1.w};
#pragma unroll
            for (int i = 0; i < 8; ++i)
#pragma unroll
                for (int j = 0; j < 8; ++j) acc[i][j] += am[i] * bj[j];
        }
    }

    float rnv[8], cnv[8];
#pragma unroll
    for (int i = 0; i < 4; ++i) {
        rnv[i]     = rn[bm + ty * 4 + i];
        rnv[4 + i] = rn[bm + 64 + ty * 4 + i];
        cnv[i]     = cn[bn + tx * 4 + i];
        cnv[4 + i] = cn[bn + 64 + tx * 4 + i];
    }
    const float4 z4 = {0.f, 0.f, 0.f, 0.f};

#pragma unroll
    for (int i = 0; i < 8; ++i) {
        const int row = bm + ((i < 4) ? ty * 4 + i : 64 + ty * 4 + (i - 4));
        const size_t rowoff = ((size_t)(row * N_L + layer)) * N_E + bn;
        float* lrow = logits + rowoff;
        float* orow = oh + rowoff;
        float4 d0, d1;
        d0.x = rnv[i] + cnv[0] - 2.0f * acc[i][0];
        d0.y = rnv[i] + cnv[1] - 2.0f * acc[i][1];
        d0.z = rnv[i] + cnv[2] - 2.0f * acc[i][2];
        d0.w = rnv[i] + cnv[3] - 2.0f * acc[i][3];
        d1.x = rnv[i] + cnv[4] - 2.0f * acc[i][4];
        d1.y = rnv[i] + cnv[5] - 2.0f * acc[i][5];
        d1.z = rnv[i] + cnv[6] - 2.0f * acc[i][6];
        d1.w = rnv[i] + cnv[7] - 2.0f * acc[i][7];
        *(float4*)(lrow + tx * 4)      = d0;
        *(float4*)(lrow + 64 + tx * 4) = d1;
        *(float4*)(orow + tx * 4)      = z4;   // zero one_hot (the 1.0 is set later by vq_update)
        *(float4*)(orow + 64 + tx * 4) = z4;

        // argmin over this thread's 8 cols, ascending global j (first-min tie-break)
        float dmin = d0.x;
        int jmin = bn + tx * 4;
        if (d0.y < dmin) { dmin = d0.y; jmin = bn + tx * 4 + 1; }
        if (d0.z < dmin) { dmin = d0.z; jmin = bn + tx * 4 + 2; }
        if (d0.w < dmin) { dmin = d0.w; jmin = bn + tx * 4 + 3; }
        if (d1.x < dmin) { dmin = d1.x; jmin = bn + 64 + tx * 4; }
        if (d1.y < dmin) { dmin = d1.y; jmin = bn + 64 + tx * 4 + 1; }
        if (d1.z < dmin) { dmin = d1.z; jmin = bn + 64 + tx * 4 + 2; }
        if (d1.w < dmin) { dmin = d1.w; jmin = bn + 64 + tx * 4 + 3; }
        unsigned long long key =
            ((unsigned long long)__float_as_uint(dmin) << 32) | (unsigned)jmin;
#pragma unroll
        for (int o = 8; o; o >>= 1) {   // reduce over the 16 tx lanes (same ty group)
            const unsigned long long other = __shfl_xor(key, o);
            if (other < key) key = other;
        }
        if (tx == 0) atomicMin(&keys[row], key);
    }
}

// ---------------------------------------------------------------- per-row update after argmin
__global__ __launch_bounds__(256) void vq_update(
    const float* __restrict__ C, const unsigned long long* __restrict__ keys,
    float* __restrict__ resid, float* __restrict__ rn,
    float* __restrict__ out_idx, float* __restrict__ oh,
    float* __restrict__ loss_ws, int layer) {
    const int b = blockIdx.x, t = threadIdx.x;
    const unsigned long long key = keys[b];
    const int j = (int)(key & 0xFFFFFFFFull);
    const float q = C[(size_t)j * E_DIM + t];
    const float r = resid[(size_t)b * E_DIM + t];
    const float nr = r - q;                      // new residual; (q-r)^2 == nr^2 -> loss term
    resid[(size_t)b * E_DIM + t] = nr;
    float s = nr * nr;
#pragma unroll
    for (int o = 32; o; o >>= 1) s += __shfl_down(s, o);
    __shared__ float red[4];
    if ((t & 63) == 0) red[t >> 6] = s;
    __syncthreads();
    if (t == 0) {
        const float tot = red[0] + red[1] + red[2] + red[3];
        rn[b] = tot;                             // ||new residual||^2 = next layer's rn
        atomicAdd(loss_ws, tot);
        out_idx[b * N_L + layer] = (float)j;
        oh[((size_t)(b * N_L + layer)) * N_E + j] = 1.0f;
    }
}

// ---------------------------------------------------------------- x_q = x - residual (in place), loss
__global__ __launch_bounds__(256) void finalize(const float* __restrict__ x,
                                                float* __restrict__ xq,
                                                const float* __restrict__ loss_ws,
                                                float* __restrict__ loss_out) {
    const int i = blockIdx.x * 256 + threadIdx.x;   // float4 index, 2048 blocks
    const float4 xv = ((const float4*)x)[i];
    const float4 rv = ((const float4*)xq)[i];
    float4 o;
    o.x = xv.x - rv.x; o.y = xv.y - rv.y; o.z = xv.z - rv.z; o.w = xv.w - rv.w;
    ((float4*)xq)[i] = o;
    if (i == 0)
        loss_out[0] = 1.25f * loss_ws[0] / (3.0f * B_SZ * E_DIM);
}

extern "C" void kernel_launch(void* const* d_in, const int* in_sizes, int n_in,
                              void* d_out, int out_size, void* d_ws, size_t ws_size,
                              hipStream_t stream) {
    (void)in_sizes; (void)n_in; (void)out_size; (void)ws_size;
    const float* x  = (const float*)d_in[0];
    const float* cb = (const float*)d_in[1];
    float* out = (float*)d_out;

    float* resid    = out + XQ_OFF;     // residual lives in the x_q output region
    float* loss_out = out + LOSS_OFF;
    float* idx_out  = out + IDX_OFF;
    float* oh       = out + OH_OFF;
    float* lg       = out + LG_OFF;

    unsigned long long* keys = (unsigned long long*)d_ws;
    float* rn      = (float*)((char*)d_ws + 65536);
    float* cn      = (float*)((char*)d_ws + 98304);
    float* loss_ws = (float*)((char*)d_ws + 147456);

    hipMemsetAsync(loss_ws, 0, sizeof(float), stream);

    init_resid<<<B_SZ, 256, 0, stream>>>(x, resid, rn);
    cb_norms<<<N_L * N_E, 64, 0, stream>>>(cb, cn);

    for (int l = 0; l < N_L; ++l) {
        hipMemsetAsync(keys, 0xFF, B_SZ * sizeof(unsigned long long), stream);
        dim3 grid(N_E / TN, B_SZ / TM);
        dist_gemm<<<grid, 256, 0, stream>>>(resid, cb + (size_t)l * N_E * E_DIM,
                                            rn, cn + l * N_E, lg, oh, keys, l);
        vq_update<<<B_SZ, 256, 0, stream>>>(cb + (size_t)l * N_E * E_DIM, keys,
                                            resid, rn, idx_out, oh, loss_ws, l);
    }
    finalize<<<B_SZ * E_DIM / 4 / 256, 256, 0, stream>>>(x, resid, loss_ws, loss_out);
}

// Round 3
// 1468.408 us; speedup vs baseline: 1.2224x; 1.1464x over previous
//
#include <hip/hip_runtime.h>
#include <stdint.h>

// Problem constants
#define B_SZ  8192
#define E_DIM 256
#define N_E   4096
#define N_L   3

// Output layout (float offsets): x_q[8192,256], loss[1], idx[8192,3],
// one_hot[8192,3,4096], logits[8192,3,4096]
#define XQ_OFF   0
#define LOSS_OFF 2097152
#define IDX_OFF  2097153
#define OH_OFF   2121729
#define LG_OFF   102785025

typedef unsigned long long u64;
typedef unsigned int u32;
typedef __attribute__((ext_vector_type(8))) __bf16 bf16x8;
typedef __attribute__((ext_vector_type(4))) float f32x4;

// Workspace (bytes): keys1 u64[8192]@0, keys2 u32[8192]@65536, rn f32[8192]@98304,
// cn f32[12288]@131072, loss f32@180224, Rhi bf16[8192*256]@262144, Rlo@4456448,
// Chi bf16[12288*256]@8650752, Clo@14942208. Total ~20.3 MB (ws observed ~GB-scale).

__device__ __forceinline__ unsigned short f2bf_rne(float f) {
    u32 u = __float_as_uint(f);
    u += 0x7FFF + ((u >> 16) & 1);
    return (unsigned short)(u >> 16);
}
__device__ __forceinline__ float bf2f(unsigned short h) {
    return __uint_as_float((u32)h << 16);
}
__device__ __forceinline__ void gl_lds16(const void* g, void* l) {
    __builtin_amdgcn_global_load_lds((const __attribute__((address_space(1))) u32*)g,
                                     (__attribute__((address_space(3))) u32*)l, 16, 0, 0);
}

// ---------------------------------------------------------------- init: residual=x, rn, bf16 splits
__global__ __launch_bounds__(256) void init_resid(const float* __restrict__ x,
                                                  float* __restrict__ resid,
                                                  float* __restrict__ rn,
                                                  unsigned short* __restrict__ Rhi,
                                                  unsigned short* __restrict__ Rlo) {
    const int b = blockIdx.x, t = threadIdx.x;
    const size_t i = (size_t)b * E_DIM + t;
    const float v = x[i];
    resid[i] = v;
    const unsigned short h = f2bf_rne(v);
    Rhi[i] = h;
    Rlo[i] = f2bf_rne(v - bf2f(h));
    float s = v * v;
#pragma unroll
    for (int o = 32; o; o >>= 1) s += __shfl_down(s, o);
    __shared__ float red[4];
    if ((t & 63) == 0) red[t >> 6] = s;
    __syncthreads();
    if (t == 0) rn[b] = red[0] + red[1] + red[2] + red[3];
}

// ---------------------------------------------------------------- codebook norms + bf16 splits
__global__ __launch_bounds__(64) void cb_norms(const float* __restrict__ cb,
                                               float* __restrict__ cn,
                                               unsigned short* __restrict__ Chi,
                                               unsigned short* __restrict__ Clo) {
    const int row = blockIdx.x;   // 0..12287
    const int t = threadIdx.x;    // 64 threads x float4
    const float4 v = ((const float4*)(cb + (size_t)row * E_DIM))[t];
    ushort4 h, l;
    h.x = f2bf_rne(v.x); l.x = f2bf_rne(v.x - bf2f(h.x));
    h.y = f2bf_rne(v.y); l.y = f2bf_rne(v.y - bf2f(h.y));
    h.z = f2bf_rne(v.z); l.z = f2bf_rne(v.z - bf2f(h.z));
    h.w = f2bf_rne(v.w); l.w = f2bf_rne(v.w - bf2f(h.w));
    ((ushort4*)(Chi + (size_t)row * E_DIM))[t] = h;
    ((ushort4*)(Clo + (size_t)row * E_DIM))[t] = l;
    float s = v.x * v.x + v.y * v.y + v.z * v.z + v.w * v.w;
#pragma unroll
    for (int o = 32; o; o >>= 1) s += __shfl_down(s, o);
    if (t == 0) cn[row] = s;
}

// ---------------------------------------------------------------- MFMA split-bf16 distance GEMM
// 128x128 tile, BK=32, 256 thr = 4 waves, each wave 64x64 (4x4 16x16x32 tiles), 3 products.
#define GT_M 128
#define GT_N 128
#define GT_K 32

__global__ __launch_bounds__(256) void dist_gemm(
    const unsigned short* __restrict__ Ahi_g, const unsigned short* __restrict__ Alo_g,
    const unsigned short* __restrict__ Bhi_g, const unsigned short* __restrict__ Blo_g,
    const float* __restrict__ rn, const float* __restrict__ cn,
    float* __restrict__ logits, float* __restrict__ oh,
    u64* __restrict__ keys1, u32* __restrict__ keys2, int layer) {
    __shared__ unsigned short Ah[GT_M * GT_K], Al[GT_M * GT_K];
    __shared__ unsigned short Bh[GT_M * GT_K], Bl[GT_M * GT_K];   // 8 KB each, 32 KB total
    const int tid = threadIdx.x;
    const int lane = tid & 63, w = tid >> 6;
    const int bm = blockIdx.y * GT_M, bn = blockIdx.x * GT_N;

    const unsigned short* A0 = Ahi_g + (size_t)bm * E_DIM;
    const unsigned short* A1 = Alo_g + (size_t)bm * E_DIM;
    const unsigned short* B0 = Bhi_g + (size_t)bn * E_DIM;
    const unsigned short* B1 = Blo_g + (size_t)bn * E_DIM;

    // staging: chunk c = w*2+tt covers rows [c*16, c*16+16); lane ℓ: row c*16+(ℓ>>2),
    // 16B piece (ℓ&3). LDS = row-major [128][32] bf16, chunk base wave-uniform.
    const int srow_off = (lane >> 2);
    const size_t gsub = (size_t)(lane & 3) * 8;

#define STAGE(k0)                                                                   \
    {                                                                               \
        _Pragma("unroll")                                                           \
        for (int tt = 0; tt < 2; ++tt) {                                            \
            const int c = w * 2 + tt;                                               \
            const int row = c * 16 + srow_off;                                      \
            const size_t ge = (size_t)row * E_DIM + (k0) + gsub;                    \
            const int lo = c * 1024;                                                \
            gl_lds16(A0 + ge, (char*)Ah + lo);                                      \
            gl_lds16(A1 + ge, (char*)Al + lo);                                      \
            gl_lds16(B0 + ge, (char*)Bh + lo);                                      \
            gl_lds16(B1 + ge, (char*)Bl + lo);                                      \
        }                                                                           \
    }

    f32x4 acc[4][4] = {};

    const int wm = (w >> 1) * 64, wn = (w & 1) * 64;
    const int fr = lane & 15;          // fragment row (A/B m/n index)
    const int fq = (lane >> 4) * 8;    // fragment k offset

    STAGE(0);
    __syncthreads();
    for (int k0 = 0;;) {
        bf16x8 ah[4], al[4], bh[4], bl[4];
#pragma unroll
        for (int mt = 0; mt < 4; ++mt) {
            ah[mt] = *(const bf16x8*)&Ah[(wm + mt * 16 + fr) * GT_K + fq];
            al[mt] = *(const bf16x8*)&Al[(wm + mt * 16 + fr) * GT_K + fq];
        }
#pragma unroll
        for (int nt = 0; nt < 4; ++nt) {
            bh[nt] = *(const bf16x8*)&Bh[(wn + nt * 16 + fr) * GT_K + fq];
            bl[nt] = *(const bf16x8*)&Bl[(wn + nt * 16 + fr) * GT_K + fq];
        }
#pragma unroll
        for (int mt = 0; mt < 4; ++mt)
#pragma unroll
            for (int nt = 0; nt < 4; ++nt) {
                acc[mt][nt] = __builtin_amdgcn_mfma_f32_16x16x32_bf16(ah[mt], bh[nt], acc[mt][nt], 0, 0, 0);
                acc[mt][nt] = __builtin_amdgcn_mfma_f32_16x16x32_bf16(ah[mt], bl[nt], acc[mt][nt], 0, 0, 0);
                acc[mt][nt] = __builtin_amdgcn_mfma_f32_16x16x32_bf16(al[mt], bh[nt], acc[mt][nt], 0, 0, 0);
            }
        k0 += GT_K;
        if (k0 == E_DIM) break;
        __syncthreads();
        STAGE(k0);
        __syncthreads();
    }

    // ---- epilogue: d = (rn+cn) - 2*acc ; write logits + oh zeros; global top-2 via atomics
    float cnv[4];
#pragma unroll
    for (int nt = 0; nt < 4; ++nt) cnv[nt] = cn[bn + wn + nt * 16 + fr];

#pragma unroll
    for (int mt = 0; mt < 4; ++mt) {
#pragma unroll
        for (int reg = 0; reg < 4; ++reg) {
            const int grow = bm + wm + mt * 16 + (lane >> 4) * 4 + reg;   // C/D row mapping (m89/m91)
            const float rv = rn[grow];
            float dv[4];
#pragma unroll
            for (int nt = 0; nt < 4; ++nt) {
                const float d = (rv + cnv[nt]) - 2.0f * acc[mt][nt][reg];
                const size_t off = ((size_t)grow * N_L + layer) * N_E + (size_t)(bn + wn + nt * 16 + fr);
                logits[off] = d;
                oh[off] = 0.0f;
                dv[nt] = d;
            }
            // per-lane top-2 of 4 (ascending j: first-min tie-break)
            float d1 = dv[0], d2 = 1e30f;
            int j1 = bn + wn + fr;
#pragma unroll
            for (int nt = 1; nt < 4; ++nt) {
                const int jj = bn + wn + nt * 16 + fr;
                if (dv[nt] < d1) { d2 = d1; d1 = dv[nt]; j1 = jj; }
                else if (dv[nt] < d2) d2 = dv[nt];
            }
            u64 p1 = ((u64)__float_as_uint(d1) << 32) | (u32)j1;
            u32 d2b = __float_as_uint(d2);
#pragma unroll
            for (int o = 1; o <= 8; o <<= 1) {   // reduce across the 16 col-lanes
                const u64 op = __shfl_xor(p1, o);
                const u32 od = __shfl_xor(d2b, o);
                const u64 hi = p1 > op ? p1 : op;
                const u32 m2 = d2b < od ? d2b : od;
                const u32 hd = (u32)(hi >> 32);
                d2b = m2 < hd ? m2 : hd;
                p1 = p1 < op ? p1 : op;
            }
            if (fr == 0) {
                const u64 old = atomicMin(&keys1[grow], p1);
                const u64 loser = old > p1 ? old : p1;
                const u32 ld = (u32)(loser >> 32);
                atomicMin(&keys2[grow], d2b < ld ? d2b : ld);
            }
        }
    }
#undef STAGE
}

// ---------------------------------------------------------------- per-row update (+ near-tie refine)
#define TAU 1e-4f
__global__ __launch_bounds__(256) void vq_update(
    const float* __restrict__ C, const float* __restrict__ cn_l,
    const u64* __restrict__ keys1, const u32* __restrict__ keys2,
    const float* __restrict__ logits,
    float* __restrict__ resid, float* __restrict__ rn,
    unsigned short* __restrict__ Rhi, unsigned short* __restrict__ Rlo,
    float* __restrict__ out_idx, float* __restrict__ oh,
    float* __restrict__ loss_ws, int layer) {
    const int b = blockIdx.x, t = threadIdx.x;
    __shared__ float red[4];
    __shared__ int s_cand[64];
    __shared__ int s_ncand;
    __shared__ float s_best;
    __shared__ int s_bestj;

    const u64 k1 = keys1[b];
    const float d1 = __uint_as_float((u32)(k1 >> 32));
    const float d2 = __uint_as_float(keys2[b]);
    int j = (int)(k1 & 0xFFFFFFFFull);

    if (d2 - d1 < TAU) {   // near-tie: re-decide with exact fp32 dots (numpy expression shape)
        if (t == 0) { s_ncand = 0; s_best = 1e30f; s_bestj = 0x7FFFFFFF; }
        __syncthreads();
        const float* lrow = logits + ((size_t)b * N_L + layer) * N_E;
        const float lim = d1 + TAU;
        for (int q = 0; q < 16; ++q) {
            const int jj = t * 16 + q;
            if (lrow[jj] <= lim) {
                const int slot = atomicAdd(&s_ncand, 1);
                if (slot < 64) s_cand[slot] = jj;
            }
        }
        __syncthreads();
        const int nc = s_ncand < 64 ? s_ncand : 64;
        const float rvt = resid[(size_t)b * E_DIM + t];
        for (int ci = 0; ci < nc; ++ci) {
            const int jj = s_cand[ci];
            float p = rvt * C[(size_t)jj * E_DIM + t];
#pragma unroll
            for (int o = 32; o; o >>= 1) p += __shfl_down(p, o);
            if ((t & 63) == 0) red[t >> 6] = p;
            __syncthreads();
            if (t == 0) {
                const float dot = red[0] + red[1] + red[2] + red[3];
                const float val = (rn[b] + cn_l[jj]) - 2.0f * dot;
                if (val < s_best || (val == s_best && jj < s_bestj)) { s_best = val; s_bestj = jj; }
            }
            __syncthreads();
        }
        j = s_bestj;
    }

    const size_t ri = (size_t)b * E_DIM + t;
    const float qv = C[(size_t)j * E_DIM + t];
    const float r = resid[ri];
    const float nr = r - qv;               // new residual; loss term = nr^2
    resid[ri] = nr;
    const unsigned short h = f2bf_rne(nr);
    Rhi[ri] = h;
    Rlo[ri] = f2bf_rne(nr - bf2f(h));
    float s = nr * nr;
#pragma unroll
    for (int o = 32; o; o >>= 1) s += __shfl_down(s, o);
    if ((t & 63) == 0) red[t >> 6] = s;
    __syncthreads();
    if (t == 0) {
        const float tot = red[0] + red[1] + red[2] + red[3];
        rn[b] = tot;                       // next layer's row norm
        atomicAdd(loss_ws, tot);
        out_idx[b * N_L + layer] = (float)j;
        oh[((size_t)b * N_L + layer) * N_E + j] = 1.0f;
    }
}

// ---------------------------------------------------------------- x_q = x - residual, loss
__global__ __launch_bounds__(256) void finalize(const float* __restrict__ x,
                                                float* __restrict__ xq,
                                                const float* __restrict__ loss_ws,
                                                float* __restrict__ loss_out) {
    const int i = blockIdx.x * 256 + threadIdx.x;
    const float4 xv = ((const float4*)x)[i];
    const float4 rv = ((const float4*)xq)[i];
    float4 o;
    o.x = xv.x - rv.x; o.y = xv.y - rv.y; o.z = xv.z - rv.z; o.w = xv.w - rv.w;
    ((float4*)xq)[i] = o;
    if (i == 0) loss_out[0] = 1.25f * loss_ws[0] / (3.0f * B_SZ * E_DIM);
}

extern "C" void kernel_launch(void* const* d_in, const int* in_sizes, int n_in,
                              void* d_out, int out_size, void* d_ws, size_t ws_size,
                              hipStream_t stream) {
    (void)in_sizes; (void)n_in; (void)out_size; (void)ws_size;
    const float* x  = (const float*)d_in[0];
    const float* cb = (const float*)d_in[1];
    float* out = (float*)d_out;

    float* resid    = out + XQ_OFF;     // residual lives in x_q region until finalize
    float* loss_out = out + LOSS_OFF;
    float* idx_out  = out + IDX_OFF;
    float* oh       = out + OH_OFF;
    float* lg       = out + LG_OFF;

    char* ws = (char*)d_ws;
    u64* keys1 = (u64*)ws;
    u32* keys2 = (u32*)(ws + 65536);
    float* rn  = (float*)(ws + 98304);
    float* cn  = (float*)(ws + 131072);
    float* loss_ws = (float*)(ws + 180224);
    unsigned short* Rhi = (unsigned short*)(ws + 262144);
    unsigned short* Rlo = (unsigned short*)(ws + 4456448);
    unsigned short* Chi = (unsigned short*)(ws + 8650752);
    unsigned short* Clo = (unsigned short*)(ws + 14942208);

    hipMemsetAsync(loss_ws, 0, sizeof(float), stream);
    init_resid<<<B_SZ, 256, 0, stream>>>(x, resid, rn, Rhi, Rlo);
    cb_norms<<<N_L * N_E, 64, 0, stream>>>(cb, cn, Chi, Clo);

    for (int l = 0; l < N_L; ++l) {
        hipMemsetAsync(keys1, 0xFF, B_SZ * sizeof(u64), stream);
        hipMemsetAsync(keys2, 0xFF, B_SZ * sizeof(u32), stream);
        dim3 grid(N_E / GT_N, B_SZ / GT_M);
        dist_gemm<<<grid, 256, 0, stream>>>(Rhi, Rlo,
                                            Chi + (size_t)l * N_E * E_DIM,
                                            Clo + (size_t)l * N_E * E_DIM,
                                            rn, cn + l * N_E, lg, oh, keys1, keys2, l);
        vq_update<<<B_SZ, 256, 0, stream>>>(cb + (size_t)l * N_E * E_DIM, cn + l * N_E,
                                            keys1, keys2, lg, resid, rn, Rhi, Rlo,
                                            idx_out, oh, loss_ws, l);
    }
    finalize<<<B_SZ * E_DIM / 4 / 256, 256, 0, stream>>>(x, resid, loss_ws, loss_out);
}